// Round 4
// baseline (8126.809 us; speedup 1.0000x reference)
//
#include <hip/hip_runtime.h>
#include <hip/hip_cooperative_groups.h>

namespace cg = cooperative_groups;

typedef _Float16 half_t;
typedef _Float16 half8 __attribute__((ext_vector_type(8)));
typedef _Float16 half4 __attribute__((ext_vector_type(4)));
typedef float float4v __attribute__((ext_vector_type(4)));

constexpr int NB = 64;    // batch
constexpr int NT = 50;    // steps
constexpr int NS = 256;   // state dim
constexpr int NA = 64;    // action dim
constexpr int NH = 256;   // hypernet hidden

constexpr float LO_SCALE = 2048.0f;   // keep lo words out of fp16 denormal range
constexpr float LO_INV   = 1.0f / 2048.0f;

// ---------------- preprocess kernels ----------------

__global__ void k_zero(unsigned* __restrict__ p, int n) {
  int idx = blockIdx.x * 256 + threadIdx.x;
  if (idx < n) p[idx] = 0u;
}

// HA/HB[t][b][h] = tanh((ctx[b]+t/50)*W1[h]+b1[h]) in fp32
__global__ void k_hahb(const float* __restrict__ ctx, const float* __restrict__ W1a,
                       const float* __restrict__ b1a, const float* __restrict__ W1b,
                       const float* __restrict__ b1b, float* __restrict__ HA,
                       float* __restrict__ HB) {
  int tb = blockIdx.x;              // t*NB + b
  int t = tb / NB, b = tb % NB;
  int h = threadIdx.x;
  float z = ctx[b] + (float)t / 50.0f;
  HA[(size_t)tb * NH + h] = tanhf(z * W1a[h] + b1a[h]);
  HB[(size_t)tb * NH + h] = tanhf(z * W1b[h] + b1b[h]);
}

// V[t][b][i] = sum_j b2b[i*NA+j] * us[b][t][j]   (fp32)
__global__ void k_v(const float* __restrict__ b2b, const float* __restrict__ us,
                    float* __restrict__ V) {
  int tb = blockIdx.x;
  int t = tb / NB, b = tb % NB;
  int i = threadIdx.x;
  __shared__ float ush[NA];
  if (i < NA) ush[i] = us[((size_t)b * NT + t) * NA + i];
  __syncthreads();
  const float* row = b2b + (size_t)i * NA;
  float s = 0.f;
#pragma unroll 8
  for (int j = 0; j < NA; ++j) s += row[j] * ush[j];
  V[(size_t)tb * NS + i] = s;
}

// W2a permute+split: [h][i*NS+k] fp32 -> Wah/Wal [i][h][k] fp16 hi / lo*2048
__global__ void k_perma(const float* __restrict__ W2a, half_t* __restrict__ Wah,
                        half_t* __restrict__ Wal) {
  int i = blockIdx.x;
  int kq = (threadIdx.x & 63) * 4;   // k-quad base
  int hs = threadIdx.x >> 6;         // 0..3
  for (int h0 = 0; h0 < NS; h0 += 4) {
    int h = h0 + hs;
    float4v v = *(const float4v*)(W2a + (size_t)h * (NS * NS) + (size_t)i * NS + kq);
    half4 oh, ol;
#pragma unroll
    for (int r = 0; r < 4; ++r) {
      half_t hi = (half_t)v[r];
      oh[r] = hi;
      ol[r] = (half_t)((v[r] - (float)hi) * LO_SCALE);
    }
    *(half4*)(Wah + ((size_t)i * NS + h) * NS + kq) = oh;
    *(half4*)(Wal + ((size_t)i * NS + h) * NS + kq) = ol;
  }
}

// W2b permute+split: [h][i*NA+j] fp32 -> [i][h][j] fp16 hi/lo
__global__ void k_permb(const float* __restrict__ W2b, half_t* __restrict__ Wbh,
                        half_t* __restrict__ Wbl) {
  int i = blockIdx.x;
  int jq = (threadIdx.x & 15) * 4;
  int hh = threadIdx.x >> 4;
  for (int h0 = 0; h0 < NH; h0 += 16) {
    int h = h0 + hh;
    float4v v = *(const float4v*)(W2b + (size_t)h * (NS * NA) + (size_t)i * NA + jq);
    half4 oh, ol;
#pragma unroll
    for (int r = 0; r < 4; ++r) {
      half_t hi = (half_t)v[r];
      oh[r] = hi;
      ol[r] = (half_t)((v[r] - (float)hi) * LO_SCALE);
    }
    *(half4*)(Wbh + ((size_t)i * NH + h) * NA + jq) = oh;
    *(half4*)(Wbl + ((size_t)i * NH + h) * NA + jq) = ol;
  }
}

// us [b][t][j] fp32 -> Uh/Ul [t][b][j] fp16
__global__ void k_u(const float* __restrict__ us, half_t* __restrict__ Uh,
                    half_t* __restrict__ Ul) {
  int t = blockIdx.x, tid = threadIdx.x;
  for (int r = 0; r < 16; ++r) {
    int idx = r * 256 + tid;       // 0..4095
    int b = idx >> 6, j = idx & 63;
    float u = us[((size_t)b * NT + t) * NA + j];
    half_t hi = (half_t)u;
    Uh[((size_t)t * NB + b) * NA + j] = hi;
    Ul[((size_t)t * NB + b) * NA + j] = (half_t)((u - (float)hi) * LO_SCALE);
  }
}

// x0 fp32 [b][k] -> Xf (fp32) + Xh/Xl fp16, parity-0 buffers
__global__ void k_x0(const float* __restrict__ x0, float* __restrict__ Xf,
                     half_t* __restrict__ Xh, half_t* __restrict__ Xl) {
  size_t idx = (size_t)blockIdx.x * 256 + threadIdx.x;
  float x = x0[idx];
  half_t hi = (half_t)x;
  Xf[idx] = x;
  Xh[idx] = hi;
  Xl[idx] = (half_t)((x - (float)hi) * LO_SCALE);
}

// ---------------- shared step body (verified in R3) ----------------
// wg = (i, hh); 4 waves, wave owns 32 h-rows (2 m-tiles). 8 waves per i across
// 2 wgs combine into Y[t][i][b] via device atomicAdd; 8th arriver finalizes.
template <bool PRE>
__device__ __forceinline__ void step_body(
    int t, int i, int hh, int tid, const half_t* __restrict__ Wlds,
    const float* __restrict__ W2a, const float* __restrict__ b2a,
    const half_t* __restrict__ Wal, const half_t* __restrict__ Wbh,
    const half_t* __restrict__ Wbl, const half_t* __restrict__ Uh,
    const half_t* __restrict__ Ul, const float* __restrict__ HA,
    const float* __restrict__ HB, const float* __restrict__ V,
    float* __restrict__ Xf, half_t* __restrict__ Xh, half_t* __restrict__ Xl,
    float* __restrict__ Y, unsigned* __restrict__ cnt, float* __restrict__ out) {
  const int lane = tid & 63, wv = tid >> 6;
  const int l15 = lane & 15, quad = lane >> 4;

  const float*  Xfc = Xf + (size_t)(t & 1) * (NB * NS);
  const half_t* Xhc = Xh + (size_t)(t & 1) * (NB * NS);
  const half_t* Xlc = Xl + (size_t)(t & 1) * (NB * NS);

  float4v accA[2][4], accC[2][4], accU[2][4], accUc[2][4];
#pragma unroll
  for (int mt = 0; mt < 2; ++mt)
#pragma unroll
    for (int nt = 0; nt < 4; ++nt) {
      accA[mt][nt] = (float4v){0.f, 0.f, 0.f, 0.f};
      accC[mt][nt] = (float4v){0.f, 0.f, 0.f, 0.f};
      accU[mt][nt] = (float4v){0.f, 0.f, 0.f, 0.f};
      accUc[mt][nt] = (float4v){0.f, 0.f, 0.f, 0.f};
    }

  // --- A-path: G[h,b] = W2a_i[h,:].x[b,:]  (hi.hi -> accA; hi.lo + lo.hi -> accC)
#pragma unroll
  for (int kb = 0; kb < 8; ++kb) {
    const int ko = kb * 32 + quad * 8;
    half8 bhi[4], blo[4];
#pragma unroll
    for (int nt = 0; nt < 4; ++nt) {
      int b = nt * 16 + l15;
      bhi[nt] = *(const half8*)(Xhc + b * NS + ko);
      blo[nt] = *(const half8*)(Xlc + b * NS + ko);
    }
#pragma unroll
    for (int mt = 0; mt < 2; ++mt) {
      const int hloc = (wv * 2 + mt) * 16 + l15;      // 0..127
      const int kc = kb * 4 + quad;
      half8 ahi = *(const half8*)(Wlds + hloc * 256 + ((kc ^ (hloc & 7)) * 8));
      half8 alo;
      if (PRE) {
        alo = *(const half8*)(Wal + (((size_t)i * NS) + hh * 128 + hloc) * NS + ko);
      } else {
        const float* src = W2a + (size_t)(hh * 128 + hloc) * (NS * NS) + (size_t)i * NS + ko;
        float4v w0 = *(const float4v*)(src);
        float4v w1 = *(const float4v*)(src + 4);
#pragma unroll
        for (int r4 = 0; r4 < 4; ++r4) {
          half_t h0v = (half_t)w0[r4];
          half_t h1v = (half_t)w1[r4];
          alo[r4]     = (half_t)((w0[r4] - (float)h0v) * LO_SCALE);
          alo[r4 + 4] = (half_t)((w1[r4] - (float)h1v) * LO_SCALE);
        }
      }
#pragma unroll
      for (int nt = 0; nt < 4; ++nt) {
        accA[mt][nt] = __builtin_amdgcn_mfma_f32_16x16x32_f16(ahi, bhi[nt], accA[mt][nt], 0, 0, 0);
        accC[mt][nt] = __builtin_amdgcn_mfma_f32_16x16x32_f16(ahi, blo[nt], accC[mt][nt], 0, 0, 0);
        accC[mt][nt] = __builtin_amdgcn_mfma_f32_16x16x32_f16(alo, bhi[nt], accC[mt][nt], 0, 0, 0);
      }
    }
  }

  // --- u-path: Gb[h,b] = W2b_i[h,:].u_t[b,:]
#pragma unroll
  for (int kb = 0; kb < 2; ++kb) {
    const int jo = kb * 32 + quad * 8;
    half8 buh[4], bul[4];
#pragma unroll
    for (int nt = 0; nt < 4; ++nt) {
      int b = nt * 16 + l15;
      buh[nt] = *(const half8*)(Uh + ((size_t)t * NB + b) * NA + jo);
      bul[nt] = *(const half8*)(Ul + ((size_t)t * NB + b) * NA + jo);
    }
#pragma unroll
    for (int mt = 0; mt < 2; ++mt) {
      const int hg = hh * 128 + (wv * 2 + mt) * 16 + l15;
      const size_t wb = ((size_t)i * NH + hg) * NA + jo;
      half8 auh = *(const half8*)(Wbh + wb);
      half8 aul = *(const half8*)(Wbl + wb);
#pragma unroll
      for (int nt = 0; nt < 4; ++nt) {
        accU[mt][nt]  = __builtin_amdgcn_mfma_f32_16x16x32_f16(auh, buh[nt], accU[mt][nt], 0, 0, 0);
        accUc[mt][nt] = __builtin_amdgcn_mfma_f32_16x16x32_f16(auh, bul[nt], accUc[mt][nt], 0, 0, 0);
        accUc[mt][nt] = __builtin_amdgcn_mfma_f32_16x16x32_f16(aul, buh[nt], accUc[mt][nt], 0, 0, 0);
      }
    }
  }

  // --- ha/hb-weighted reduction over this wave's 32 h-rows
  float part[4] = {0.f, 0.f, 0.f, 0.f};
#pragma unroll
  for (int mt = 0; mt < 2; ++mt) {
    int hg = hh * 128 + (wv * 2 + mt) * 16 + quad * 4;
#pragma unroll
    for (int nt = 0; nt < 4; ++nt) {
      int b = nt * 16 + l15;
      float4v ha4 = *(const float4v*)(HA + ((size_t)t * NB + b) * NH + hg);
      float4v hb4 = *(const float4v*)(HB + ((size_t)t * NB + b) * NH + hg);
#pragma unroll
      for (int r = 0; r < 4; ++r) {
        float ga = accA[mt][nt][r] + accC[mt][nt][r] * LO_INV;
        float gb = accU[mt][nt][r] + accUc[mt][nt][r] * LO_INV;
        part[nt] += ha4[r] * ga + hb4[r] * gb;
      }
    }
  }
#pragma unroll
  for (int nt = 0; nt < 4; ++nt) {
    part[nt] += __shfl_xor(part[nt], 16);
    part[nt] += __shfl_xor(part[nt], 32);
  }

  float* Yrow = Y + ((size_t)t * NS + i) * NB;
  if (quad == 0) {
#pragma unroll
    for (int nt = 0; nt < 4; ++nt) atomicAdd(&Yrow[nt * 16 + l15], part[nt]);
  }

  // --- bias_a partial: b2a_i . x_t (fp32, hh==0 wgs only; wave wv covers k quarter)
  if (hh == 0) {
    float bp = 0.f;
    const float* w  = b2a + (size_t)i * NS + wv * 64;
    const float* xr = Xfc + (size_t)lane * NS + wv * 64;
#pragma unroll
    for (int kq = 0; kq < 16; ++kq) {
      float4v wv4 = *(const float4v*)(w + kq * 4);
      float4v xv4 = *(const float4v*)(xr + kq * 4);
      bp += wv4[0] * xv4[0] + wv4[1] * xv4[1] + wv4[2] * xv4[2] + wv4[3] * xv4[3];
    }
    atomicAdd(&Yrow[lane], bp);
  }

  // --- per-wave completion signal; 8th wave for this i finalizes
  __threadfence();
  int old = 0;
  if (lane == 0) old = (int)atomicAdd(&cnt[t * NS + i], 1u);
  old = __shfl(old, 0);
  if (old == 7) {
    int b = lane;
    float y = atomicAdd(&Yrow[b], 0.0f);     // coherent read
    float xf = y + V[((size_t)t * NB + b) * NS + i];
    out[((size_t)b * NT + t) * NS + i] = xf;
    size_t nxt = (size_t)((t + 1) & 1) * (NB * NS) + (size_t)b * NS + i;
    half_t hi = (half_t)xf;
    Xf[nxt] = xf;
    Xh[nxt] = hi;
    Xl[nxt] = (half_t)((xf - (float)hi) * LO_SCALE);
  }
}

// --- W-hi half-slice staging into LDS (16B-chunk XOR swizzle: c -> c^(row&7))
template <bool PRE>
__device__ __forceinline__ void stage_whi(int i, int hh, int tid,
                                          const float* __restrict__ W2a,
                                          const half_t* __restrict__ Wah,
                                          half_t* __restrict__ Wlds) {
  for (int r = 0; r < 16; ++r) {
    int m = r * 256 + tid;          // chunk id 0..4095
    int row = m >> 5, c = m & 31;   // row 0..127, chunk 0..31
    half8 v;
    if (PRE) {
      v = *(const half8*)(Wah + (((size_t)i * NS) + hh * 128 + row) * NS + c * 8);
    } else {
      const float* src = W2a + (size_t)(hh * 128 + row) * (NS * NS) + (size_t)i * NS + c * 8;
      float4v w0 = *(const float4v*)(src);
      float4v w1 = *(const float4v*)(src + 4);
#pragma unroll
      for (int r4 = 0; r4 < 4; ++r4) { v[r4] = (half_t)w0[r4]; v[r4 + 4] = (half_t)w1[r4]; }
    }
    *(half8*)(Wlds + row * 256 + ((c ^ (row & 7)) * 8)) = v;
  }
}

// ---------------- per-step kernel (fallback path, verified R3) ----------------
template <bool PRE>
__launch_bounds__(256, 2)
__global__ void k_step(int t, const float* __restrict__ W2a, const float* __restrict__ b2a,
                       const half_t* __restrict__ Wah, const half_t* __restrict__ Wal,
                       const half_t* __restrict__ Wbh, const half_t* __restrict__ Wbl,
                       const half_t* __restrict__ Uh, const half_t* __restrict__ Ul,
                       const float* __restrict__ HA, const float* __restrict__ HB,
                       const float* __restrict__ V, float* __restrict__ Xf,
                       half_t* __restrict__ Xh, half_t* __restrict__ Xl,
                       float* __restrict__ Y, unsigned* __restrict__ cnt,
                       float* __restrict__ out) {
  __shared__ half_t Wlds[128 * 256];          // 64 KiB static
  const int tid = threadIdx.x;
  const int i  = blockIdx.x >> 1;
  const int hh = blockIdx.x & 1;
  stage_whi<PRE>(i, hh, tid, W2a, Wah, Wlds);
  __syncthreads();
  step_body<PRE>(t, i, hh, tid, Wlds, W2a, b2a, Wal, Wbh, Wbl, Uh, Ul,
                 HA, HB, V, Xf, Xh, Xl, Y, cnt, out);
}

// ---------------- persistent cooperative rollout ----------------
// grid=512 (2 wg/CU, 64 KiB static LDS each = 128 KiB/CU). W-hi staged ONCE,
// then 50 steps separated by grid.sync(). No dynamic LDS, no FuncSetAttribute.
template <bool PRE>
__launch_bounds__(256, 2)
__global__ void k_roll(const float* __restrict__ W2a, const float* __restrict__ b2a,
                       const half_t* __restrict__ Wah, const half_t* __restrict__ Wal,
                       const half_t* __restrict__ Wbh, const half_t* __restrict__ Wbl,
                       const half_t* __restrict__ Uh, const half_t* __restrict__ Ul,
                       const float* __restrict__ HA, const float* __restrict__ HB,
                       const float* __restrict__ V, float* __restrict__ Xf,
                       half_t* __restrict__ Xh, half_t* __restrict__ Xl,
                       float* __restrict__ Y, unsigned* __restrict__ cnt,
                       float* __restrict__ out) {
  __shared__ half_t Wlds[128 * 256];          // 64 KiB static
  const int tid = threadIdx.x;
  const int i  = blockIdx.x >> 1;
  const int hh = blockIdx.x & 1;
  stage_whi<PRE>(i, hh, tid, W2a, Wah, Wlds);
  __syncthreads();

  cg::grid_group grid = cg::this_grid();
  for (int t = 0; t < NT; ++t) {
    step_body<PRE>(t, i, hh, tid, Wlds, W2a, b2a, Wal, Wbh, Wbl, Uh, Ul,
                   HA, HB, V, Xf, Xh, Xl, Y, cnt, out);
    __threadfence();
    grid.sync();
  }
}

// ---------------- launch ----------------

extern "C" void kernel_launch(void* const* d_in, const int* in_sizes, int n_in,
                              void* d_out, int out_size, void* d_ws, size_t ws_size,
                              hipStream_t stream) {
  const float* x0  = (const float*)d_in[0];
  const float* ctx = (const float*)d_in[1];
  const float* us  = (const float*)d_in[2];
  const float* W1a = (const float*)d_in[3];
  const float* b1a = (const float*)d_in[4];
  const float* W2a = (const float*)d_in[5];
  const float* b2a = (const float*)d_in[6];
  const float* W1b = (const float*)d_in[7];
  const float* b1b = (const float*)d_in[8];
  const float* W2b = (const float*)d_in[9];
  const float* b2b = (const float*)d_in[10];
  float* out = (float*)d_out;

  const size_t szWa  = (size_t)NS * NS * NS * 2;      // 33,554,432 each
  const size_t szWb  = (size_t)NS * NH * NA * 2;      //  8,388,608 each
  const size_t szU   = (size_t)NT * NB * NA * 2;      //    409,600 each
  const size_t szH   = (size_t)NT * NB * NH * 4;      //  3,276,800 each
  const size_t szV   = (size_t)NT * NB * NS * 4;      //  3,276,800
  const size_t szXf  = (size_t)2 * NB * NS * 4;       //    131,072
  const size_t szXh  = (size_t)2 * NB * NS * 2;       //     65,536 each
  const size_t szY   = (size_t)NT * NS * NB * 4;      //  3,276,800
  const size_t szCnt = (size_t)NT * NS * 4;           //     51,200

  const size_t fixed = szWb * 2 + szU * 2 + szH * 2 + szV + szXf + szXh * 2 + szY + szCnt;
  const bool pre = (ws_size >= fixed + 2 * szWa);

  char* p = (char*)d_ws;
  half_t *Wah = nullptr, *Wal = nullptr;
  if (pre) { Wah = (half_t*)p; p += szWa; Wal = (half_t*)p; p += szWa; }
  half_t* Wbh = (half_t*)p; p += szWb;
  half_t* Wbl = (half_t*)p; p += szWb;
  half_t* Uh  = (half_t*)p; p += szU;
  half_t* Ul  = (half_t*)p; p += szU;
  float*  HAg = (float*)p;  p += szH;
  float*  HBg = (float*)p;  p += szH;
  float*  Vg  = (float*)p;  p += szV;
  float*  Xf  = (float*)p;  p += szXf;
  half_t* Xh  = (half_t*)p; p += szXh;
  half_t* Xl  = (half_t*)p; p += szXh;
  float*  Yg  = (float*)p;  p += szY;
  unsigned* cnt = (unsigned*)p;

  {
    int nwords = (int)((szY + szCnt) / 4);
    k_zero<<<(nwords + 255) / 256, 256, 0, stream>>>((unsigned*)Yg, nwords);
  }
  k_hahb<<<NT * NB, NH, 0, stream>>>(ctx, W1a, b1a, W1b, b1b, HAg, HBg);
  k_v<<<NT * NB, NS, 0, stream>>>(b2b, us, Vg);
  k_permb<<<NS, 256, 0, stream>>>(W2b, Wbh, Wbl);
  k_u<<<NT, 256, 0, stream>>>(us, Uh, Ul);
  k_x0<<<NB, NS, 0, stream>>>(x0, Xf, Xh, Xl);
  if (pre) k_perma<<<NS, 256, 0, stream>>>(W2a, Wah, Wal);

  void* args[] = {(void*)&W2a, (void*)&b2a, (void*)&Wah, (void*)&Wal,
                  (void*)&Wbh, (void*)&Wbl, (void*)&Uh,  (void*)&Ul,
                  (void*)&HAg, (void*)&HBg, (void*)&Vg,  (void*)&Xf,
                  (void*)&Xh,  (void*)&Xl,  (void*)&Yg,  (void*)&cnt, (void*)&out};

  hipError_t e;
  if (pre) {
    e = hipLaunchCooperativeKernel((void*)k_roll<true>, dim3(2 * NS), dim3(256), args, 0, stream);
  } else {
    e = hipLaunchCooperativeKernel((void*)k_roll<false>, dim3(2 * NS), dim3(256), args, 0, stream);
  }

  if (e != hipSuccess) {
    // fallback: verified stream-ordered per-step path (R3)
    if (pre) {
      for (int t = 0; t < NT; ++t)
        k_step<true><<<2 * NS, 256, 0, stream>>>(t, W2a, b2a, Wah, Wal, Wbh, Wbl, Uh, Ul,
                                                 HAg, HBg, Vg, Xf, Xh, Xl, Yg, cnt, out);
    } else {
      for (int t = 0; t < NT; ++t)
        k_step<false><<<2 * NS, 256, 0, stream>>>(t, W2a, b2a, Wah, Wal, Wbh, Wbl, Uh, Ul,
                                                  HAg, HBg, Vg, Xf, Xh, Xl, Yg, cnt, out);
    }
  }
}

// Round 5
// 4145.666 us; speedup vs baseline: 1.9603x; 1.9603x over previous
//
#include <hip/hip_runtime.h>

typedef _Float16 half_t;
typedef _Float16 half8 __attribute__((ext_vector_type(8)));
typedef _Float16 half4 __attribute__((ext_vector_type(4)));
typedef _Float16 half16 __attribute__((ext_vector_type(16)));
typedef float float4v __attribute__((ext_vector_type(4)));
typedef unsigned long long u64;

constexpr int NB = 64;    // batch
constexpr int NT = 50;    // steps
constexpr int NS = 256;   // state dim
constexpr int NA = 64;    // action dim
constexpr int NH = 256;   // hypernet hidden

constexpr float LO_SCALE = 2048.0f;
constexpr float LO_INV   = 1.0f / 2048.0f;

// ---- coherent-point (cache-bypassing) access helpers: no fences, no L2 inv ----
__device__ __forceinline__ u64 aload64(const void* p) {
  return __hip_atomic_load((const u64*)p, __ATOMIC_RELAXED, __HIP_MEMORY_SCOPE_SYSTEM);
}
__device__ __forceinline__ unsigned aload32(const void* p) {
  return __hip_atomic_load((const unsigned*)p, __ATOMIC_RELAXED, __HIP_MEMORY_SCOPE_SYSTEM);
}
__device__ __forceinline__ void astore32(void* p, unsigned v) {
  __hip_atomic_store((unsigned*)p, v, __ATOMIC_RELAXED, __HIP_MEMORY_SCOPE_SYSTEM);
}
#define WAITVM() asm volatile("s_waitcnt vmcnt(0)" ::: "memory")

// ---------------- preprocess kernels ----------------

__global__ void k_zero(unsigned* __restrict__ p, int n) {
  int idx = blockIdx.x * 256 + threadIdx.x;
  if (idx < n) p[idx] = 0u;
}

__global__ void k_hahb(const float* __restrict__ ctx, const float* __restrict__ W1a,
                       const float* __restrict__ b1a, const float* __restrict__ W1b,
                       const float* __restrict__ b1b, float* __restrict__ HA,
                       float* __restrict__ HB) {
  int tb = blockIdx.x;
  int t = tb / NB, b = tb % NB;
  int h = threadIdx.x;
  float z = ctx[b] + (float)t / 50.0f;
  HA[(size_t)tb * NH + h] = tanhf(z * W1a[h] + b1a[h]);
  HB[(size_t)tb * NH + h] = tanhf(z * W1b[h] + b1b[h]);
}

__global__ void k_v(const float* __restrict__ b2b, const float* __restrict__ us,
                    float* __restrict__ V) {
  int tb = blockIdx.x;
  int t = tb / NB, b = tb % NB;
  int i = threadIdx.x;
  __shared__ float ush[NA];
  if (i < NA) ush[i] = us[((size_t)b * NT + t) * NA + i];
  __syncthreads();
  const float* row = b2b + (size_t)i * NA;
  float s = 0.f;
#pragma unroll 8
  for (int j = 0; j < NA; ++j) s += row[j] * ush[j];
  V[(size_t)tb * NS + i] = s;
}

__global__ void k_perma(const float* __restrict__ W2a, half_t* __restrict__ Wah,
                        half_t* __restrict__ Wal) {
  int i = blockIdx.x;
  int kq = (threadIdx.x & 63) * 4;
  int hs = threadIdx.x >> 6;
  for (int h0 = 0; h0 < NS; h0 += 4) {
    int h = h0 + hs;
    float4v v = *(const float4v*)(W2a + (size_t)h * (NS * NS) + (size_t)i * NS + kq);
    half4 oh, ol;
#pragma unroll
    for (int r = 0; r < 4; ++r) {
      half_t hi = (half_t)v[r];
      oh[r] = hi;
      ol[r] = (half_t)((v[r] - (float)hi) * LO_SCALE);
    }
    *(half4*)(Wah + ((size_t)i * NS + h) * NS + kq) = oh;
    *(half4*)(Wal + ((size_t)i * NS + h) * NS + kq) = ol;
  }
}

__global__ void k_permb(const float* __restrict__ W2b, half_t* __restrict__ Wbh,
                        half_t* __restrict__ Wbl) {
  int i = blockIdx.x;
  int jq = (threadIdx.x & 15) * 4;
  int hh = threadIdx.x >> 4;
  for (int h0 = 0; h0 < NH; h0 += 16) {
    int h = h0 + hh;
    float4v v = *(const float4v*)(W2b + (size_t)h * (NS * NA) + (size_t)i * NA + jq);
    half4 oh, ol;
#pragma unroll
    for (int r = 0; r < 4; ++r) {
      half_t hi = (half_t)v[r];
      oh[r] = hi;
      ol[r] = (half_t)((v[r] - (float)hi) * LO_SCALE);
    }
    *(half4*)(Wbh + ((size_t)i * NH + h) * NA + jq) = oh;
    *(half4*)(Wbl + ((size_t)i * NH + h) * NA + jq) = ol;
  }
}

__global__ void k_u(const float* __restrict__ us, half_t* __restrict__ Uh,
                    half_t* __restrict__ Ul) {
  int t = blockIdx.x, tid = threadIdx.x;
  for (int r = 0; r < 16; ++r) {
    int idx = r * 256 + tid;
    int b = idx >> 6, j = idx & 63;
    float u = us[((size_t)b * NT + t) * NA + j];
    half_t hi = (half_t)u;
    Uh[((size_t)t * NB + b) * NA + j] = hi;
    Ul[((size_t)t * NB + b) * NA + j] = (half_t)((u - (float)hi) * LO_SCALE);
  }
}

// x0 -> Xf fp32 + Xp packed (hi | lo<<16), parity-0
__global__ void k_x0(const float* __restrict__ x0, float* __restrict__ Xf,
                     unsigned* __restrict__ Xp) {
  size_t idx = (size_t)blockIdx.x * 256 + threadIdx.x;
  float x = x0[idx];
  half_t hi = (half_t)x;
  half_t lo = (half_t)((x - (float)hi) * LO_SCALE);
  Xf[idx] = x;
  union { half_t h[2]; unsigned u; } P;
  P.h[0] = hi; P.h[1] = lo;
  Xp[idx] = P.u;
}

// --- W-hi half-slice staging into LDS (16B-chunk XOR swizzle: c -> c^(row&7))
template <bool PRE>
__device__ __forceinline__ void stage_whi(int i, int hh, int tid,
                                          const float* __restrict__ W2a,
                                          const half_t* __restrict__ Wah,
                                          half_t* __restrict__ Wlds) {
  for (int r = 0; r < 16; ++r) {
    int m = r * 256 + tid;
    int row = m >> 5, c = m & 31;
    half8 v;
    if (PRE) {
      v = *(const half8*)(Wah + (((size_t)i * NS) + hh * 128 + row) * NS + c * 8);
    } else {
      const float* src = W2a + (size_t)(hh * 128 + row) * (NS * NS) + (size_t)i * NS + c * 8;
      float4v w0 = *(const float4v*)(src);
      float4v w1 = *(const float4v*)(src + 4);
#pragma unroll
      for (int r4 = 0; r4 < 4; ++r4) { v[r4] = (half_t)w0[r4]; v[r4 + 4] = (half_t)w1[r4]; }
    }
    *(half8*)(Wlds + row * 256 + ((c ^ (row & 7)) * 8)) = v;
  }
}

// ---------------- persistent rollout ----------------
// grid=512: wg=(i=blk>>1, hh=blk&1), 256 thr (4 waves), 64 KiB static LDS (2 wg/CU).
// Phase 0: u-path for ALL t (x-independent, W2b frags in regs) -> atomicAdd Y[t].
// Phase 1: t-loop; x published via system-scope atomics; done[t] counter is the sync.
template <bool PRE>
__launch_bounds__(256, 2)
__global__ void k_roll(const float* __restrict__ W2a, const float* __restrict__ b2a,
                       const half_t* __restrict__ Wah, const half_t* __restrict__ Wal,
                       const half_t* __restrict__ Wbh, const half_t* __restrict__ Wbl,
                       const half_t* __restrict__ Uh, const half_t* __restrict__ Ul,
                       const float* __restrict__ HA, const float* __restrict__ HB,
                       const float* __restrict__ V, float* __restrict__ Xf,
                       unsigned* __restrict__ Xp, float* __restrict__ Y,
                       unsigned* __restrict__ cnt, unsigned* __restrict__ done,
                       float* __restrict__ out) {
  __shared__ half_t Wlds[128 * 256];
  const int tid = threadIdx.x;
  const int i  = blockIdx.x >> 1;
  const int hh = blockIdx.x & 1;
  const int lane = tid & 63, wv = tid >> 6;
  const int l15 = lane & 15, quad = lane >> 4;

  stage_whi<PRE>(i, hh, tid, W2a, Wah, Wlds);
  __syncthreads();

  // ===== Phase 0: u-path, all t (wave covers 32 h-rows x all 64 b) =====
  {
    half8 auh[2][2], aul[2][2];   // [kb][mt]
#pragma unroll
    for (int kb = 0; kb < 2; ++kb) {
      const int jo = kb * 32 + quad * 8;
#pragma unroll
      for (int mt = 0; mt < 2; ++mt) {
        const int hg = hh * 128 + (wv * 2 + mt) * 16 + l15;
        const size_t wb = ((size_t)i * NH + hg) * NA + jo;
        auh[kb][mt] = *(const half8*)(Wbh + wb);
        aul[kb][mt] = *(const half8*)(Wbl + wb);
      }
    }
    for (int t = 0; t < NT; ++t) {
      float4v aU[2][4], aUc[2][4];
#pragma unroll
      for (int mt = 0; mt < 2; ++mt)
#pragma unroll
        for (int nt = 0; nt < 4; ++nt) {
          aU[mt][nt] = (float4v){0.f, 0.f, 0.f, 0.f};
          aUc[mt][nt] = (float4v){0.f, 0.f, 0.f, 0.f};
        }
#pragma unroll
      for (int kb = 0; kb < 2; ++kb) {
        const int jo = kb * 32 + quad * 8;
        half8 buh[4], bul[4];
#pragma unroll
        for (int nt = 0; nt < 4; ++nt) {
          int b = nt * 16 + l15;
          buh[nt] = *(const half8*)(Uh + ((size_t)t * NB + b) * NA + jo);
          bul[nt] = *(const half8*)(Ul + ((size_t)t * NB + b) * NA + jo);
        }
#pragma unroll
        for (int mt = 0; mt < 2; ++mt)
#pragma unroll
          for (int nt = 0; nt < 4; ++nt) {
            aU[mt][nt]  = __builtin_amdgcn_mfma_f32_16x16x32_f16(auh[kb][mt], buh[nt], aU[mt][nt], 0, 0, 0);
            aUc[mt][nt] = __builtin_amdgcn_mfma_f32_16x16x32_f16(auh[kb][mt], bul[nt], aUc[mt][nt], 0, 0, 0);
            aUc[mt][nt] = __builtin_amdgcn_mfma_f32_16x16x32_f16(aul[kb][mt], buh[nt], aUc[mt][nt], 0, 0, 0);
          }
      }
      float part[4] = {0.f, 0.f, 0.f, 0.f};
#pragma unroll
      for (int mt = 0; mt < 2; ++mt) {
        int hg = hh * 128 + (wv * 2 + mt) * 16 + quad * 4;
#pragma unroll
        for (int nt = 0; nt < 4; ++nt) {
          int b = nt * 16 + l15;
          float4v hb4 = *(const float4v*)(HB + ((size_t)t * NB + b) * NH + hg);
#pragma unroll
          for (int r = 0; r < 4; ++r)
            part[nt] += hb4[r] * (aU[mt][nt][r] + aUc[mt][nt][r] * LO_INV);
        }
      }
#pragma unroll
      for (int nt = 0; nt < 4; ++nt) {
        part[nt] += __shfl_xor(part[nt], 16);
        part[nt] += __shfl_xor(part[nt], 32);
      }
      float* Yrow = Y + ((size_t)t * NS + i) * NB;
      if (quad == 0) {
#pragma unroll
        for (int nt = 0; nt < 4; ++nt) atomicAdd(&Yrow[nt * 16 + l15], part[nt]);
      }
    }
  }

  // ===== Phase 1: rollout. Wave covers 64 h-rows (r2) x 32 b (bh). =====
  const int r2 = wv >> 1, bh = wv & 1;
  for (int t = 0; t < NT; ++t) {
    if (t > 0) {
      while (aload32(done + (t - 1)) < 256u) __builtin_amdgcn_s_sleep(2);
    }
    const int par = t & 1;
    const unsigned* Xpc = Xp + (size_t)par * (NB * NS);
    const float*    Xfc = Xf + (size_t)par * (NB * NS);

    float4v accA[4][2], accC[4][2];
#pragma unroll
    for (int mt = 0; mt < 4; ++mt)
#pragma unroll
      for (int nt = 0; nt < 2; ++nt) {
        accA[mt][nt] = (float4v){0.f, 0.f, 0.f, 0.f};
        accC[mt][nt] = (float4v){0.f, 0.f, 0.f, 0.f};
      }

#pragma unroll
    for (int kb = 0; kb < 8; ++kb) {
      const int ko = kb * 32 + quad * 8;      // word index (packed hi|lo)
      half8 bhi[2], blo[2];
#pragma unroll
      for (int nt = 0; nt < 2; ++nt) {
        int b = bh * 32 + nt * 16 + l15;
        const unsigned* q = Xpc + b * NS + ko;
        union { u64 u[4]; half16 v; } U;
#pragma unroll
        for (int j = 0; j < 4; ++j) U.u[j] = aload64(q + 2 * j);
        bhi[nt] = __builtin_shufflevector(U.v, U.v, 0, 2, 4, 6, 8, 10, 12, 14);
        blo[nt] = __builtin_shufflevector(U.v, U.v, 1, 3, 5, 7, 9, 11, 13, 15);
      }
#pragma unroll
      for (int mt = 0; mt < 4; ++mt) {
        const int hloc = r2 * 64 + mt * 16 + l15;      // 0..127
        const int kc = kb * 4 + quad;
        half8 ahi = *(const half8*)(Wlds + hloc * 256 + ((kc ^ (hloc & 7)) * 8));
        half8 alo;
        if (PRE) {
          alo = *(const half8*)(Wal + (((size_t)i * NS) + hh * 128 + hloc) * NS + ko);
        } else {
          const float* src = W2a + (size_t)(hh * 128 + hloc) * (NS * NS) + (size_t)i * NS + ko;
          float4v w0 = *(const float4v*)(src);
          float4v w1 = *(const float4v*)(src + 4);
#pragma unroll
          for (int r4 = 0; r4 < 4; ++r4) {
            half_t h0v = (half_t)w0[r4];
            half_t h1v = (half_t)w1[r4];
            alo[r4]     = (half_t)((w0[r4] - (float)h0v) * LO_SCALE);
            alo[r4 + 4] = (half_t)((w1[r4] - (float)h1v) * LO_SCALE);
          }
        }
#pragma unroll
        for (int nt = 0; nt < 2; ++nt) {
          accA[mt][nt] = __builtin_amdgcn_mfma_f32_16x16x32_f16(ahi, bhi[nt], accA[mt][nt], 0, 0, 0);
          accC[mt][nt] = __builtin_amdgcn_mfma_f32_16x16x32_f16(ahi, blo[nt], accC[mt][nt], 0, 0, 0);
          accC[mt][nt] = __builtin_amdgcn_mfma_f32_16x16x32_f16(alo, bhi[nt], accC[mt][nt], 0, 0, 0);
        }
      }
    }

    float* Yrow = Y + ((size_t)t * NS + i) * NB;

    // bias_a partial (hh==0 wgs): b2a_i . x_t, fp32 via coherent 8B loads
    if (hh == 0) {
      int bb = tid & 63;
      const float* w  = b2a + (size_t)i * NS + wv * 64;
      const float* xr = Xfc + (size_t)bb * NS + wv * 64;
      float bp = 0.f;
#pragma unroll
      for (int j = 0; j < 16; ++j) {
        float4v w4 = *(const float4v*)(w + j * 4);
        union { u64 q; float f[2]; } A, B;
        A.q = aload64(xr + j * 4);
        B.q = aload64(xr + j * 4 + 2);
        bp += w4[0] * A.f[0] + w4[1] * A.f[1] + w4[2] * B.f[0] + w4[3] * B.f[1];
      }
      atomicAdd(&Yrow[bb], bp);
    }

    // ha-weighted reduction over this wave's 64 h-rows
    float part[2] = {0.f, 0.f};
#pragma unroll
    for (int mt = 0; mt < 4; ++mt) {
      int hg = hh * 128 + r2 * 64 + mt * 16 + quad * 4;
#pragma unroll
      for (int nt = 0; nt < 2; ++nt) {
        int b = bh * 32 + nt * 16 + l15;
        float4v ha4 = *(const float4v*)(HA + ((size_t)t * NB + b) * NH + hg);
#pragma unroll
        for (int r = 0; r < 4; ++r)
          part[nt] += ha4[r] * (accA[mt][nt][r] + accC[mt][nt][r] * LO_INV);
      }
    }
#pragma unroll
    for (int nt = 0; nt < 2; ++nt) {
      part[nt] += __shfl_xor(part[nt], 16);
      part[nt] += __shfl_xor(part[nt], 32);
    }
    if (quad == 0) {
#pragma unroll
      for (int nt = 0; nt < 2; ++nt)
        atomicAdd(&Yrow[bh * 32 + nt * 16 + l15], part[nt]);
    }

    WAITVM();   // own Y/bias atomics complete before signaling
    int old = 0;
    if (lane == 0) old = (int)atomicAdd(&cnt[t * NS + i], 1u);
    old = __shfl(old, 0);
    if (old == 7) {
      int b = lane;
      float y = atomicAdd(&Yrow[b], 0.0f);
      float xf = y + V[((size_t)t * NB + b) * NS + i];
      out[((size_t)b * NT + t) * NS + i] = xf;
      size_t nxt = (size_t)((t + 1) & 1) * (NB * NS) + (size_t)b * NS + i;
      half_t hi = (half_t)xf;
      half_t lo = (half_t)((xf - (float)hi) * LO_SCALE);
      union { half_t h[2]; unsigned u; } P;
      P.h[0] = hi; P.h[1] = lo;
      astore32(Xp + nxt, P.u);
      union { float f; unsigned u; } F; F.f = xf;
      astore32(Xf + nxt, F.u);
      WAITVM();   // X published before done-signal
      if (lane == 0) atomicAdd(&done[t], 1u);
    }
  }
}

// ---------------- launch ----------------

extern "C" void kernel_launch(void* const* d_in, const int* in_sizes, int n_in,
                              void* d_out, int out_size, void* d_ws, size_t ws_size,
                              hipStream_t stream) {
  const float* x0  = (const float*)d_in[0];
  const float* ctx = (const float*)d_in[1];
  const float* us  = (const float*)d_in[2];
  const float* W1a = (const float*)d_in[3];
  const float* b1a = (const float*)d_in[4];
  const float* W2a = (const float*)d_in[5];
  const float* b2a = (const float*)d_in[6];
  const float* W1b = (const float*)d_in[7];
  const float* b1b = (const float*)d_in[8];
  const float* W2b = (const float*)d_in[9];
  const float* b2b = (const float*)d_in[10];
  float* out = (float*)d_out;

  const size_t szWa  = (size_t)NS * NS * NS * 2;      // 33,554,432 each
  const size_t szWb  = (size_t)NS * NH * NA * 2;      //  8,388,608 each
  const size_t szU   = (size_t)NT * NB * NA * 2;      //    409,600 each
  const size_t szH   = (size_t)NT * NB * NH * 4;      //  3,276,800 each
  const size_t szV   = (size_t)NT * NB * NS * 4;      //  3,276,800
  const size_t szXf  = (size_t)2 * NB * NS * 4;       //    131,072
  const size_t szXp  = (size_t)2 * NB * NS * 4;       //    131,072
  const size_t szY   = (size_t)NT * NS * NB * 4;      //  3,276,800
  const size_t szCnt = (size_t)NT * NS * 4;           //     51,200
  const size_t szDone = 1024;                         // NT*4 padded

  const size_t fixed = szWb * 2 + szU * 2 + szH * 2 + szV + szXf + szXp + szY + szCnt + szDone;
  const bool pre = (ws_size >= fixed + 2 * szWa);

  char* p = (char*)d_ws;
  half_t *Wah = nullptr, *Wal = nullptr;
  if (pre) { Wah = (half_t*)p; p += szWa; Wal = (half_t*)p; p += szWa; }
  half_t* Wbh = (half_t*)p; p += szWb;
  half_t* Wbl = (half_t*)p; p += szWb;
  half_t* Uh  = (half_t*)p; p += szU;
  half_t* Ul  = (half_t*)p; p += szU;
  float*  HAg = (float*)p;  p += szH;
  float*  HBg = (float*)p;  p += szH;
  float*  Vg  = (float*)p;  p += szV;
  float*  Xf  = (float*)p;  p += szXf;
  unsigned* Xp = (unsigned*)p; p += szXp;
  float*  Yg  = (float*)p;  p += szY;          // zero block starts here
  unsigned* cnt = (unsigned*)p; p += szCnt;
  unsigned* done = (unsigned*)p;

  {
    int nwords = (int)((szY + szCnt + szDone) / 4);
    k_zero<<<(nwords + 255) / 256, 256, 0, stream>>>((unsigned*)Yg, nwords);
  }
  k_hahb<<<NT * NB, NH, 0, stream>>>(ctx, W1a, b1a, W1b, b1b, HAg, HBg);
  k_v<<<NT * NB, NS, 0, stream>>>(b2b, us, Vg);
  k_permb<<<NS, 256, 0, stream>>>(W2b, Wbh, Wbl);
  k_u<<<NT, 256, 0, stream>>>(us, Uh, Ul);
  k_x0<<<NB, NS, 0, stream>>>(x0, Xf, Xp);
  if (pre) k_perma<<<NS, 256, 0, stream>>>(W2a, Wah, Wal);

  void* args[] = {(void*)&W2a, (void*)&b2a, (void*)&Wah, (void*)&Wal,
                  (void*)&Wbh, (void*)&Wbl, (void*)&Uh,  (void*)&Ul,
                  (void*)&HAg, (void*)&HBg, (void*)&Vg,  (void*)&Xf,
                  (void*)&Xp,  (void*)&Yg,  (void*)&cnt, (void*)&done, (void*)&out};

  // cooperative launch for the residency guarantee only (no grid.sync used)
  hipError_t e;
  if (pre) {
    e = hipLaunchCooperativeKernel((void*)k_roll<true>, dim3(2 * NS), dim3(256), args, 0, stream);
    if (e != hipSuccess)
      k_roll<true><<<2 * NS, 256, 0, stream>>>(W2a, b2a, Wah, Wal, Wbh, Wbl, Uh, Ul,
                                               HAg, HBg, Vg, Xf, Xp, Yg, cnt, done, out);
  } else {
    e = hipLaunchCooperativeKernel((void*)k_roll<false>, dim3(2 * NS), dim3(256), args, 0, stream);
    if (e != hipSuccess)
      k_roll<false><<<2 * NS, 256, 0, stream>>>(W2a, b2a, Wah, Wal, Wbh, Wbl, Uh, Ul,
                                                HAg, HBg, Vg, Xf, Xp, Yg, cnt, done, out);
  }
}

// Round 6
// 1627.302 us; speedup vs baseline: 4.9940x; 2.5476x over previous
//
#include <hip/hip_runtime.h>

typedef _Float16 half_t;
typedef _Float16 half8 __attribute__((ext_vector_type(8)));
typedef _Float16 half4 __attribute__((ext_vector_type(4)));
typedef _Float16 half16 __attribute__((ext_vector_type(16)));
typedef float float4v __attribute__((ext_vector_type(4)));
typedef unsigned uint4v __attribute__((ext_vector_type(4)));
typedef unsigned long long u64;

constexpr int NB = 64;    // batch
constexpr int NT = 50;    // steps
constexpr int NS = 256;   // state dim
constexpr int NA = 64;    // action dim
constexpr int NH = 256;   // hypernet hidden

constexpr float LO_SCALE = 2048.0f;
constexpr float LO_INV   = 1.0f / 2048.0f;

// ---- coherent-point access helpers ----
__device__ __forceinline__ unsigned aload32(const void* p) {
  return __hip_atomic_load((const unsigned*)p, __ATOMIC_RELAXED, __HIP_MEMORY_SCOPE_SYSTEM);
}
__device__ __forceinline__ void astore32(void* p, unsigned v) {
  __hip_atomic_store((unsigned*)p, v, __ATOMIC_RELAXED, __HIP_MEMORY_SCOPE_SYSTEM);
}
#define WAITVM() asm volatile("s_waitcnt vmcnt(0)" ::: "memory")

// ---------------- preprocess kernels ----------------

__global__ void k_zero(unsigned* __restrict__ p, int n) {
  int idx = blockIdx.x * 256 + threadIdx.x;
  if (idx < n) p[idx] = 0u;
}

__global__ void k_hahb(const float* __restrict__ ctx, const float* __restrict__ W1a,
                       const float* __restrict__ b1a, const float* __restrict__ W1b,
                       const float* __restrict__ b1b, float* __restrict__ HA,
                       float* __restrict__ HB) {
  int tb = blockIdx.x;
  int t = tb / NB, b = tb % NB;
  int h = threadIdx.x;
  float z = ctx[b] + (float)t / 50.0f;
  HA[(size_t)tb * NH + h] = tanhf(z * W1a[h] + b1a[h]);
  HB[(size_t)tb * NH + h] = tanhf(z * W1b[h] + b1b[h]);
}

__global__ void k_v(const float* __restrict__ b2b, const float* __restrict__ us,
                    float* __restrict__ V) {
  int tb = blockIdx.x;
  int t = tb / NB, b = tb % NB;
  int i = threadIdx.x;
  __shared__ float ush[NA];
  if (i < NA) ush[i] = us[((size_t)b * NT + t) * NA + i];
  __syncthreads();
  const float* row = b2b + (size_t)i * NA;
  float s = 0.f;
#pragma unroll 8
  for (int j = 0; j < NA; ++j) s += row[j] * ush[j];
  V[(size_t)tb * NS + i] = s;
}

__global__ void k_perma(const float* __restrict__ W2a, half_t* __restrict__ Wah,
                        half_t* __restrict__ Wal) {
  int i = blockIdx.x;
  int kq = (threadIdx.x & 63) * 4;
  int hs = threadIdx.x >> 6;
  for (int h0 = 0; h0 < NS; h0 += 4) {
    int h = h0 + hs;
    float4v v = *(const float4v*)(W2a + (size_t)h * (NS * NS) + (size_t)i * NS + kq);
    half4 oh, ol;
#pragma unroll
    for (int r = 0; r < 4; ++r) {
      half_t hi = (half_t)v[r];
      oh[r] = hi;
      ol[r] = (half_t)((v[r] - (float)hi) * LO_SCALE);
    }
    *(half4*)(Wah + ((size_t)i * NS + h) * NS + kq) = oh;
    *(half4*)(Wal + ((size_t)i * NS + h) * NS + kq) = ol;
  }
}

__global__ void k_permb(const float* __restrict__ W2b, half_t* __restrict__ Wbh,
                        half_t* __restrict__ Wbl) {
  int i = blockIdx.x;
  int jq = (threadIdx.x & 15) * 4;
  int hh = threadIdx.x >> 4;
  for (int h0 = 0; h0 < NH; h0 += 16) {
    int h = h0 + hh;
    float4v v = *(const float4v*)(W2b + (size_t)h * (NS * NA) + (size_t)i * NA + jq);
    half4 oh, ol;
#pragma unroll
    for (int r = 0; r < 4; ++r) {
      half_t hi = (half_t)v[r];
      oh[r] = hi;
      ol[r] = (half_t)((v[r] - (float)hi) * LO_SCALE);
    }
    *(half4*)(Wbh + ((size_t)i * NH + h) * NA + jq) = oh;
    *(half4*)(Wbl + ((size_t)i * NH + h) * NA + jq) = ol;
  }
}

__global__ void k_u(const float* __restrict__ us, half_t* __restrict__ Uh,
                    half_t* __restrict__ Ul) {
  int t = blockIdx.x, tid = threadIdx.x;
  for (int r = 0; r < 16; ++r) {
    int idx = r * 256 + tid;
    int b = idx >> 6, j = idx & 63;
    float u = us[((size_t)b * NT + t) * NA + j];
    half_t hi = (half_t)u;
    Uh[((size_t)t * NB + b) * NA + j] = hi;
    Ul[((size_t)t * NB + b) * NA + j] = (half_t)((u - (float)hi) * LO_SCALE);
  }
}

// x0 -> XpS buffer 0, packed (hi | lo<<16)
__global__ void k_x0(const float* __restrict__ x0, unsigned* __restrict__ XpS) {
  size_t idx = (size_t)blockIdx.x * 256 + threadIdx.x;
  float x = x0[idx];
  half_t hi = (half_t)x;
  half_t lo = (half_t)((x - (float)hi) * LO_SCALE);
  union { half_t h[2]; unsigned u; } P;
  P.h[0] = hi; P.h[1] = lo;
  XpS[idx] = P.u;
}

// --- W-hi half-slice staging into LDS (16B-chunk XOR swizzle: c -> c^(row&7))
template <bool PRE>
__device__ __forceinline__ void stage_whi(int i, int hh, int tid,
                                          const float* __restrict__ W2a,
                                          const half_t* __restrict__ Wah,
                                          half_t* __restrict__ Wlds) {
  for (int r = 0; r < 16; ++r) {
    int m = r * 256 + tid;
    int row = m >> 5, c = m & 31;
    half8 v;
    if (PRE) {
      v = *(const half8*)(Wah + (((size_t)i * NS) + hh * 128 + row) * NS + c * 8);
    } else {
      const float* src = W2a + (size_t)(hh * 128 + row) * (NS * NS) + (size_t)i * NS + c * 8;
      float4v w0 = *(const float4v*)(src);
      float4v w1 = *(const float4v*)(src + 4);
#pragma unroll
      for (int r4 = 0; r4 < 4; ++r4) { v[r4] = (half_t)w0[r4]; v[r4 + 4] = (half_t)w1[r4]; }
    }
    *(half8*)(Wlds + row * 256 + ((c ^ (row & 7)) * 8)) = v;
  }
}

// ---------------- persistent rollout ----------------
// grid=512: wg=(i=blk>>1, hh=blk&1), 256 thr (4 waves), 64 KiB static LDS (2 wg/CU).
// Phase 0: u-path for ALL t (x-independent) -> atomicAdd Y[t].
// Phase 1: per-step X buffers; producers publish via system-scope stores; global-last
// finalizer writes 8 replicated flags; wave 0 of each wg polls, others barrier.
template <bool PRE>
__launch_bounds__(256, 2)
__global__ void k_roll(const float* __restrict__ W2a, const float* __restrict__ b2a,
                       const half_t* __restrict__ Wah, const half_t* __restrict__ Wal,
                       const half_t* __restrict__ Wbh, const half_t* __restrict__ Wbl,
                       const half_t* __restrict__ Uh, const half_t* __restrict__ Ul,
                       const float* __restrict__ HA, const float* __restrict__ HB,
                       const float* __restrict__ V, unsigned* __restrict__ XpS,
                       float* __restrict__ Y, unsigned* __restrict__ cnt,
                       unsigned* __restrict__ done, unsigned* __restrict__ flag,
                       float* __restrict__ out) {
  __shared__ half_t Wlds[128 * 256];
  const int tid = threadIdx.x;
  const int i  = blockIdx.x >> 1;
  const int hh = blockIdx.x & 1;
  const int lane = tid & 63, wv = tid >> 6;
  const int l15 = lane & 15, quad = lane >> 4;

  stage_whi<PRE>(i, hh, tid, W2a, Wah, Wlds);
  __syncthreads();

  // ===== Phase 0: u-path, all t (wave covers 32 h-rows x all 64 b) =====
  {
    half8 auh[2][2], aul[2][2];   // [kb][mt]
#pragma unroll
    for (int kb = 0; kb < 2; ++kb) {
      const int jo = kb * 32 + quad * 8;
#pragma unroll
      for (int mt = 0; mt < 2; ++mt) {
        const int hg = hh * 128 + (wv * 2 + mt) * 16 + l15;
        const size_t wb = ((size_t)i * NH + hg) * NA + jo;
        auh[kb][mt] = *(const half8*)(Wbh + wb);
        aul[kb][mt] = *(const half8*)(Wbl + wb);
      }
    }
    for (int t = 0; t < NT; ++t) {
      float4v aU[2][4], aUc[2][4];
#pragma unroll
      for (int mt = 0; mt < 2; ++mt)
#pragma unroll
        for (int nt = 0; nt < 4; ++nt) {
          aU[mt][nt] = (float4v){0.f, 0.f, 0.f, 0.f};
          aUc[mt][nt] = (float4v){0.f, 0.f, 0.f, 0.f};
        }
#pragma unroll
      for (int kb = 0; kb < 2; ++kb) {
        const int jo = kb * 32 + quad * 8;
        half8 buh[4], bul[4];
#pragma unroll
        for (int nt = 0; nt < 4; ++nt) {
          int b = nt * 16 + l15;
          buh[nt] = *(const half8*)(Uh + ((size_t)t * NB + b) * NA + jo);
          bul[nt] = *(const half8*)(Ul + ((size_t)t * NB + b) * NA + jo);
        }
#pragma unroll
        for (int mt = 0; mt < 2; ++mt)
#pragma unroll
          for (int nt = 0; nt < 4; ++nt) {
            aU[mt][nt]  = __builtin_amdgcn_mfma_f32_16x16x32_f16(auh[kb][mt], buh[nt], aU[mt][nt], 0, 0, 0);
            aUc[mt][nt] = __builtin_amdgcn_mfma_f32_16x16x32_f16(auh[kb][mt], bul[nt], aUc[mt][nt], 0, 0, 0);
            aUc[mt][nt] = __builtin_amdgcn_mfma_f32_16x16x32_f16(aul[kb][mt], buh[nt], aUc[mt][nt], 0, 0, 0);
          }
      }
      float part[4] = {0.f, 0.f, 0.f, 0.f};
#pragma unroll
      for (int mt = 0; mt < 2; ++mt) {
        int hg = hh * 128 + (wv * 2 + mt) * 16 + quad * 4;
#pragma unroll
        for (int nt = 0; nt < 4; ++nt) {
          int b = nt * 16 + l15;
          float4v hb4 = *(const float4v*)(HB + ((size_t)t * NB + b) * NH + hg);
#pragma unroll
          for (int r = 0; r < 4; ++r)
            part[nt] += hb4[r] * (aU[mt][nt][r] + aUc[mt][nt][r] * LO_INV);
        }
      }
#pragma unroll
      for (int nt = 0; nt < 4; ++nt) {
        part[nt] += __shfl_xor(part[nt], 16);
        part[nt] += __shfl_xor(part[nt], 32);
      }
      float* Yrow = Y + ((size_t)t * NS + i) * NB;
      if (quad == 0) {
#pragma unroll
        for (int nt = 0; nt < 4; ++nt) atomicAdd(&Yrow[nt * 16 + l15], part[nt]);
      }
    }
  }

  // ===== Phase 1: rollout. Wave covers 64 h-rows (r2) x 32 b (bh). =====
  const int r2 = wv >> 1, bh = wv & 1;
  for (int t = 0; t < NT; ++t) {
    if (t > 0) {
      if (wv == 0) {
        const unsigned* f = flag + ((size_t)(t - 1) * 8 + (blockIdx.x & 7)) * 32;
        while (aload32(f) == 0u) __builtin_amdgcn_s_sleep(4);
      }
      __syncthreads();
    }
    const unsigned* Xpc = XpS + (size_t)t * (NB * NS);   // fresh buffer: cached loads OK

    float4v accA[4][2], accC[4][2];
#pragma unroll
    for (int mt = 0; mt < 4; ++mt)
#pragma unroll
      for (int nt = 0; nt < 2; ++nt) {
        accA[mt][nt] = (float4v){0.f, 0.f, 0.f, 0.f};
        accC[mt][nt] = (float4v){0.f, 0.f, 0.f, 0.f};
      }

#pragma unroll
    for (int kb = 0; kb < 8; ++kb) {
      const int ko = kb * 32 + quad * 8;      // word index (packed hi|lo)
      half8 bhi[2], blo[2];
#pragma unroll
      for (int nt = 0; nt < 2; ++nt) {
        int b = bh * 32 + nt * 16 + l15;
        const unsigned* q = Xpc + b * NS + ko;
        union { uint4v u4[2]; half16 v; } U;
        U.u4[0] = *(const uint4v*)(q);
        U.u4[1] = *(const uint4v*)(q + 4);
        bhi[nt] = __builtin_shufflevector(U.v, U.v, 0, 2, 4, 6, 8, 10, 12, 14);
        blo[nt] = __builtin_shufflevector(U.v, U.v, 1, 3, 5, 7, 9, 11, 13, 15);
      }
#pragma unroll
      for (int mt = 0; mt < 4; ++mt) {
        const int hloc = r2 * 64 + mt * 16 + l15;      // 0..127
        const int kc = kb * 4 + quad;
        half8 ahi = *(const half8*)(Wlds + hloc * 256 + ((kc ^ (hloc & 7)) * 8));
        half8 alo;
        if (PRE) {
          alo = *(const half8*)(Wal + (((size_t)i * NS) + hh * 128 + hloc) * NS + ko);
        } else {
          const float* src = W2a + (size_t)(hh * 128 + hloc) * (NS * NS) + (size_t)i * NS + ko;
          float4v w0 = *(const float4v*)(src);
          float4v w1 = *(const float4v*)(src + 4);
#pragma unroll
          for (int r4 = 0; r4 < 4; ++r4) {
            half_t h0v = (half_t)w0[r4];
            half_t h1v = (half_t)w1[r4];
            alo[r4]     = (half_t)((w0[r4] - (float)h0v) * LO_SCALE);
            alo[r4 + 4] = (half_t)((w1[r4] - (float)h1v) * LO_SCALE);
          }
        }
#pragma unroll
        for (int nt = 0; nt < 2; ++nt) {
          accA[mt][nt] = __builtin_amdgcn_mfma_f32_16x16x32_f16(ahi, bhi[nt], accA[mt][nt], 0, 0, 0);
          accC[mt][nt] = __builtin_amdgcn_mfma_f32_16x16x32_f16(ahi, blo[nt], accC[mt][nt], 0, 0, 0);
          accC[mt][nt] = __builtin_amdgcn_mfma_f32_16x16x32_f16(alo, bhi[nt], accC[mt][nt], 0, 0, 0);
        }
      }
    }

    float* Yrow = Y + ((size_t)t * NS + i) * NB;

    // bias_a partial (hh==0 wgs): b2a_i . x_t from packed X (cached loads)
    if (hh == 0) {
      int bb = tid & 63;
      const float*    w  = b2a + (size_t)i * NS + wv * 64;
      const unsigned* xr = Xpc + (size_t)bb * NS + wv * 64;
      float bp = 0.f;
#pragma unroll
      for (int j = 0; j < 16; ++j) {
        float4v w4 = *(const float4v*)(w + j * 4);
        uint4v  xw = *(const uint4v*)(xr + j * 4);
#pragma unroll
        for (int r = 0; r < 4; ++r) {
          union { unsigned u; half_t h[2]; } P; P.u = xw[r];
          bp += w4[r] * ((float)P.h[0] + (float)P.h[1] * LO_INV);
        }
      }
      atomicAdd(&Yrow[bb], bp);
    }

    // ha-weighted reduction over this wave's 64 h-rows
    float part[2] = {0.f, 0.f};
#pragma unroll
    for (int mt = 0; mt < 4; ++mt) {
      int hg = hh * 128 + r2 * 64 + mt * 16 + quad * 4;
#pragma unroll
      for (int nt = 0; nt < 2; ++nt) {
        int b = bh * 32 + nt * 16 + l15;
        float4v ha4 = *(const float4v*)(HA + ((size_t)t * NB + b) * NH + hg);
#pragma unroll
        for (int r = 0; r < 4; ++r)
          part[nt] += ha4[r] * (accA[mt][nt][r] + accC[mt][nt][r] * LO_INV);
      }
    }
#pragma unroll
    for (int nt = 0; nt < 2; ++nt) {
      part[nt] += __shfl_xor(part[nt], 16);
      part[nt] += __shfl_xor(part[nt], 32);
    }
    if (quad == 0) {
#pragma unroll
      for (int nt = 0; nt < 2; ++nt)
        atomicAdd(&Yrow[bh * 32 + nt * 16 + l15], part[nt]);
    }

    WAITVM();   // own Y/bias atomics complete before signaling
    int old = 0;
    if (lane == 0) old = (int)atomicAdd(&cnt[t * NS + i], 1u);
    old = __shfl(old, 0);
    if (old == 7) {
      int b = lane;
      float y = atomicAdd(&Yrow[b], 0.0f);
      float xf = y + V[((size_t)t * NB + b) * NS + i];
      out[((size_t)b * NT + t) * NS + i] = xf;
      half_t hi = (half_t)xf;
      half_t lo = (half_t)((xf - (float)hi) * LO_SCALE);
      union { half_t h[2]; unsigned u; } P;
      P.h[0] = hi; P.h[1] = lo;
      astore32(XpS + (size_t)(t + 1) * (NB * NS) + (size_t)b * NS + i, P.u);
      WAITVM();   // X published (and out stored) before done-signal
      unsigned o2 = 0;
      if (lane == 0) o2 = (unsigned)atomicAdd(&done[t], 1u);
      o2 = __shfl((int)o2, 0);
      if (o2 == 255u && lane < 8)
        astore32(flag + ((size_t)t * 8 + lane) * 32, 1u);   // 8 replicated lines
    }
  }
}

// ---------------- launch ----------------

extern "C" void kernel_launch(void* const* d_in, const int* in_sizes, int n_in,
                              void* d_out, int out_size, void* d_ws, size_t ws_size,
                              hipStream_t stream) {
  const float* x0  = (const float*)d_in[0];
  const float* ctx = (const float*)d_in[1];
  const float* us  = (const float*)d_in[2];
  const float* W1a = (const float*)d_in[3];
  const float* b1a = (const float*)d_in[4];
  const float* W2a = (const float*)d_in[5];
  const float* b2a = (const float*)d_in[6];
  const float* W1b = (const float*)d_in[7];
  const float* b1b = (const float*)d_in[8];
  const float* W2b = (const float*)d_in[9];
  const float* b2b = (const float*)d_in[10];
  float* out = (float*)d_out;

  const size_t szWa  = (size_t)NS * NS * NS * 2;        // 33,554,432 each
  const size_t szWb  = (size_t)NS * NH * NA * 2;        //  8,388,608 each
  const size_t szU   = (size_t)NT * NB * NA * 2;        //    409,600 each
  const size_t szH   = (size_t)NT * NB * NH * 4;        //  3,276,800 each
  const size_t szV   = (size_t)NT * NB * NS * 4;        //  3,276,800
  const size_t szXpS = (size_t)(NT + 1) * NB * NS * 4;  //  3,342,336
  const size_t szY   = (size_t)NT * NS * NB * 4;        //  3,276,800
  const size_t szCnt = (size_t)NT * NS * 4;             //     51,200
  const size_t szDone = 256;
  const size_t szFlag = (size_t)NT * 8 * 32 * 4;        //     51,200

  const size_t fixed = szWb * 2 + szU * 2 + szH * 2 + szV + szXpS + szY + szCnt + szDone + szFlag;
  const bool pre = (ws_size >= fixed + 2 * szWa);

  char* p = (char*)d_ws;
  half_t *Wah = nullptr, *Wal = nullptr;
  if (pre) { Wah = (half_t*)p; p += szWa; Wal = (half_t*)p; p += szWa; }
  half_t* Wbh = (half_t*)p; p += szWb;
  half_t* Wbl = (half_t*)p; p += szWb;
  half_t* Uh  = (half_t*)p; p += szU;
  half_t* Ul  = (half_t*)p; p += szU;
  float*  HAg = (float*)p;  p += szH;
  float*  HBg = (float*)p;  p += szH;
  float*  Vg  = (float*)p;  p += szV;
  unsigned* XpS = (unsigned*)p; p += szXpS;
  float*  Yg  = (float*)p;  p += szY;            // zero block starts here
  unsigned* cnt = (unsigned*)p; p += szCnt;
  unsigned* done = (unsigned*)p; p += szDone;
  unsigned* flag = (unsigned*)p;

  {
    int nwords = (int)((szY + szCnt + szDone + szFlag) / 4);
    k_zero<<<(nwords + 255) / 256, 256, 0, stream>>>((unsigned*)Yg, nwords);
  }
  k_hahb<<<NT * NB, NH, 0, stream>>>(ctx, W1a, b1a, W1b, b1b, HAg, HBg);
  k_v<<<NT * NB, NS, 0, stream>>>(b2b, us, Vg);
  k_permb<<<NS, 256, 0, stream>>>(W2b, Wbh, Wbl);
  k_u<<<NT, 256, 0, stream>>>(us, Uh, Ul);
  k_x0<<<NB, NS, 0, stream>>>(x0, XpS);
  if (pre) k_perma<<<NS, 256, 0, stream>>>(W2a, Wah, Wal);

  void* args[] = {(void*)&W2a, (void*)&b2a, (void*)&Wah, (void*)&Wal,
                  (void*)&Wbh, (void*)&Wbl, (void*)&Uh,  (void*)&Ul,
                  (void*)&HAg, (void*)&HBg, (void*)&Vg,  (void*)&XpS,
                  (void*)&Yg,  (void*)&cnt, (void*)&done, (void*)&flag, (void*)&out};

  // cooperative launch for the residency guarantee only (no grid.sync used)
  hipError_t e;
  if (pre) {
    e = hipLaunchCooperativeKernel((void*)k_roll<true>, dim3(2 * NS), dim3(256), args, 0, stream);
    if (e != hipSuccess)
      k_roll<true><<<2 * NS, 256, 0, stream>>>(W2a, b2a, Wah, Wal, Wbh, Wbl, Uh, Ul,
                                               HAg, HBg, Vg, XpS, Yg, cnt, done, flag, out);
  } else {
    e = hipLaunchCooperativeKernel((void*)k_roll<false>, dim3(2 * NS), dim3(256), args, 0, stream);
    if (e != hipSuccess)
      k_roll<false><<<2 * NS, 256, 0, stream>>>(W2a, b2a, Wah, Wal, Wbh, Wbl, Uh, Ul,
                                                HAg, HBg, Vg, XpS, Yg, cnt, done, flag, out);
  }
}